// Round 1
// baseline (494.148 us; speedup 1.0000x reference)
//
#include <hip/hip_runtime.h>
#include <hip/hip_bf16.h>
#include <math.h>

// Problem constants (FunctionNPairLoss): N=8192 rows, K=128 dims, 64 classes.
#define KD 128
#define NCLS 64
#define TI 64
#define TJ 64
#define JSPLIT 4

// ---------------- init: zero Z, label_sum, cnt, cursor ----------------
__global__ void init_kernel(float* Z, float* lsum, int* cnt, int* cur, int N) {
    int t = blockIdx.x * 256 + threadIdx.x;
    if (t < N) Z[t] = 0.0f;
    if (t < NCLS) { lsum[t] = 0.0f; cnt[t] = 0; cur[t] = 0; }
}

// ---------------- prep: sq[i] = ||e_i||^2, count labels ----------------
__global__ __launch_bounds__(256) void prep_kernel(const float* __restrict__ emb,
                                                   const int* __restrict__ lab,
                                                   float* __restrict__ sq,
                                                   int* __restrict__ cnt, int N) {
    int w = (blockIdx.x * blockDim.x + threadIdx.x) >> 6;  // one wave per row
    int lane = threadIdx.x & 63;
    if (w >= N) return;
    float x0 = emb[w * KD + lane];
    float x1 = emb[w * KD + 64 + lane];
    float s = x0 * x0 + x1 * x1;
    for (int m = 32; m; m >>= 1) s += __shfl_xor(s, m, 64);
    if (lane == 0) {
        sq[w] = s;
        atomicAdd(&cnt[lab[w]], 1);
    }
}

// ---------------- offsets: serial exclusive scan over 64 counts ----------------
__global__ void off_kernel(const int* __restrict__ cnt, int* __restrict__ off) {
    if (threadIdx.x == 0) {
        int s = 0;
        for (int c = 0; c < NCLS; ++c) { off[c] = s; s += cnt[c]; }
    }
}

// ---------------- scatter: member lists per label ----------------
__global__ void scatter_kernel(const int* __restrict__ lab, const int* __restrict__ off,
                               int* __restrict__ cur, int* __restrict__ list, int N) {
    int i = blockIdx.x * 256 + threadIdx.x;
    if (i < N) {
        int c = lab[i];
        int p = atomicAdd(&cur[c], 1);
        list[off[c] + p] = i;
    }
}

// ---------------- main Z pass: Z[i] = sum_{j: lab[j]!=lab[i]} exp(D[i,j]) ----------------
// Tiled 64x64, 4x4 register blocking, fp32. grid = (JSPLIT, N/TI), block = 256.
__global__ __launch_bounds__(256) void z_kernel(const float* __restrict__ emb,
                                                const int* __restrict__ lab,
                                                const float* __restrict__ sq,
                                                float* __restrict__ Z, int N) {
    __shared__ float As[TI][132];  // full K=128, row stride 132 (16B aligned, bank stride 4)
    __shared__ float Bs[TJ][68];   // half K=64, row stride 68

    const int tid = threadIdx.x;
    const int tx = tid & 15;       // j dimension
    const int ty = tid >> 4;       // i dimension
    const int js = blockIdx.x;
    const int i0 = blockIdx.y * TI;

    // stage A tile (64 rows x 128 K), coalesced float4
    for (int it = 0; it < 8; ++it) {
        int f = tid + 256 * it;            // float4 index 0..2047
        int row = f >> 5;
        int k4 = (f & 31) << 2;
        float4 v = *(const float4*)&emb[(size_t)(i0 + row) * KD + k4];
        *(float4*)&As[row][k4] = v;
    }

    float sqi[4]; int labi[4];
#pragma unroll
    for (int r = 0; r < 4; ++r) {
        int i = i0 + ty + 16 * r;
        sqi[r] = sq[i];
        labi[r] = lab[i];
    }
    float zsum[4] = {0.f, 0.f, 0.f, 0.f};
    __syncthreads();

    const int jChunk = N / JSPLIT;
    const int jBeg = js * jChunk;
    for (int jt = 0; jt < jChunk / TJ; ++jt) {
        int j0 = jBeg + jt * TJ;
        float acc[4][4];
#pragma unroll
        for (int r = 0; r < 4; ++r)
#pragma unroll
            for (int c = 0; c < 4; ++c) acc[r][c] = 0.f;

        for (int kk = 0; kk < KD; kk += 64) {
            // stage B half-tile (64 rows x 64 K)
            for (int it = 0; it < 4; ++it) {
                int f = tid + 256 * it;        // float4 index 0..1023
                int row = f >> 4;
                int k4 = (f & 15) << 2;
                float4 v = *(const float4*)&emb[(size_t)(j0 + row) * KD + kk + k4];
                *(float4*)&Bs[row][k4] = v;
            }
            __syncthreads();
#pragma unroll 4
            for (int k = 0; k < 64; ++k) {
                float a0 = As[ty][kk + k];
                float a1 = As[ty + 16][kk + k];
                float a2 = As[ty + 32][kk + k];
                float a3 = As[ty + 48][kk + k];
                float b0 = Bs[tx][k];
                float b1 = Bs[tx + 16][k];
                float b2 = Bs[tx + 32][k];
                float b3 = Bs[tx + 48][k];
                acc[0][0] += a0 * b0; acc[0][1] += a0 * b1; acc[0][2] += a0 * b2; acc[0][3] += a0 * b3;
                acc[1][0] += a1 * b0; acc[1][1] += a1 * b1; acc[1][2] += a1 * b2; acc[1][3] += a1 * b3;
                acc[2][0] += a2 * b0; acc[2][1] += a2 * b1; acc[2][2] += a2 * b2; acc[2][3] += a2 * b3;
                acc[3][0] += a3 * b0; acc[3][1] += a3 * b1; acc[3][2] += a3 * b2; acc[3][3] += a3 * b3;
            }
            __syncthreads();
        }

        // epilogue: masked exp + row accumulation
#pragma unroll
        for (int c = 0; c < 4; ++c) {
            int j = j0 + tx + 16 * c;
            float sqj = sq[j];
            int labj = lab[j];
#pragma unroll
            for (int r = 0; r < 4; ++r) {
                if (labj != labi[r]) {
                    float D = sqi[r] + sqj - 2.0f * acc[r][c];
                    zsum[r] += __expf(D);
                }
            }
        }
    }

    // reduce over tx (16 consecutive lanes within wave), then atomic into Z
#pragma unroll
    for (int r = 0; r < 4; ++r) {
        float v = zsum[r];
        v += __shfl_xor(v, 8, 64);
        v += __shfl_xor(v, 4, 64);
        v += __shfl_xor(v, 2, 64);
        v += __shfl_xor(v, 1, 64);
        if (tx == 0) atomicAdd(&Z[i0 + ty + 16 * r], v);
    }
}

// ---------------- pairs: per-label same-label pair losses ----------------
// grid = NCLS * 4 blocks; block b handles label (b&63), stripe (b>>6) of pair space.
__global__ __launch_bounds__(256) void pair_kernel(const float* __restrict__ emb,
                                                   const float* __restrict__ sq,
                                                   const float* __restrict__ Z,
                                                   const int* __restrict__ cnt,
                                                   const int* __restrict__ off,
                                                   const int* __restrict__ list,
                                                   float* __restrict__ lsum) {
    int c = blockIdx.x & (NCLS - 1);
    int s = blockIdx.x >> 6;
    int k = cnt[c];
    int base = off[c];
    long total = (long)k * k;
    float part = 0.f;

    for (long t = threadIdx.x + (long)s * 256; t < total; t += 1024) {
        int p = (int)(t / k);
        int q = (int)(t - (long)p * k);
        if (p >= q) continue;
        int a = list[base + p];
        int b = list[base + q];
        const float4* pa = (const float4*)&emb[(size_t)a * KD];
        const float4* pb = (const float4*)&emb[(size_t)b * KD];
        float dot = 0.f;
#pragma unroll 8
        for (int u = 0; u < KD / 4; ++u) {
            float4 va = pa[u];
            float4 vb = pb[u];
            dot += va.x * vb.x + va.y * vb.y + va.z * vb.z + va.w * vb.w;
        }
        int anc = min(a, b);
        float D = sq[a] + sq[b] - 2.0f * dot;
        part += log1pf(Z[anc] * __expf(-D));
    }

    __shared__ float red[4];
    for (int m = 32; m; m >>= 1) part += __shfl_xor(part, m, 64);
    int lane = threadIdx.x & 63;
    int w = threadIdx.x >> 6;
    if (lane == 0) red[w] = part;
    __syncthreads();
    if (threadIdx.x == 0) {
        atomicAdd(&lsum[c], red[0] + red[1] + red[2] + red[3]);
    }
}

// ---------------- finalize: per-label mean, mean over valid labels ----------------
__global__ void fin_kernel(const float* __restrict__ lsum, const int* __restrict__ cnt,
                           float* __restrict__ out) {
    int c = threadIdx.x;  // 64 threads, one wave
    float mean = 0.f;
    int valid = 0;
    if (c < NCLS) {
        long k = cnt[c];
        long np = k * (k - 1) / 2;
        if (np > 0) { mean = lsum[c] / (float)np; valid = 1; }
    }
    float sm = mean;
    int sv = valid;
    for (int m = 32; m; m >>= 1) {
        sm += __shfl_xor(sm, m, 64);
        sv += __shfl_xor(sv, m, 64);
    }
    if (c == 0) out[0] = sm / (float)max(sv, 1);
}

extern "C" void kernel_launch(void* const* d_in, const int* in_sizes, int n_in,
                              void* d_out, int out_size, void* d_ws, size_t ws_size,
                              hipStream_t stream) {
    const float* emb = (const float*)d_in[0];
    const int* lab = (const int*)d_in[1];
    float* out = (float*)d_out;
    const int N = in_sizes[1];  // 8192

    // workspace layout (floats/ints, all 4B)
    float* ws = (float*)d_ws;
    float* sq = ws;                    // N
    float* Z = ws + N;                 // N
    float* lsum = ws + 2 * N;          // 64
    int* cnt = (int*)(ws + 2 * N + NCLS);
    int* off = cnt + NCLS;
    int* cur = off + NCLS;
    int* list = cur + NCLS;            // N

    init_kernel<<<(N + 255) / 256, 256, 0, stream>>>(Z, lsum, cnt, cur, N);
    prep_kernel<<<N / 4, 256, 0, stream>>>(emb, lab, sq, cnt, N);
    off_kernel<<<1, 64, 0, stream>>>(cnt, off);
    scatter_kernel<<<(N + 255) / 256, 256, 0, stream>>>(lab, off, cur, list, N);
    dim3 zgrid(JSPLIT, N / TI);
    z_kernel<<<zgrid, 256, 0, stream>>>(emb, lab, sq, Z, N);
    pair_kernel<<<NCLS * 4, 256, 0, stream>>>(emb, sq, Z, cnt, off, list, lsum);
    fin_kernel<<<1, 64, 0, stream>>>(lsum, cnt, out);
}

// Round 2
// 188.666 us; speedup vs baseline: 2.6192x; 2.6192x over previous
//
#include <hip/hip_runtime.h>
#include <hip/hip_bf16.h>
#include <math.h>

// Problem constants (FunctionNPairLoss): N=8192 rows, K=128 dims, 64 classes.
#define KD 128
#define NCLS 64
#define JSPLIT 8
#define PCAP 224

typedef __attribute__((ext_vector_type(8))) short short8;
typedef __attribute__((ext_vector_type(4))) short short4_t;
typedef __attribute__((ext_vector_type(4))) float f32x4;

__device__ inline void gload_lds16(const void* g, void* l) {
    __builtin_amdgcn_global_load_lds((const __attribute__((address_space(1))) unsigned int*)g,
                                     (__attribute__((address_space(3))) unsigned int*)l,
                                     16, 0, 0);
}

__device__ inline float b2f(short s) {
    union { float f; unsigned int u; } x;
    x.u = ((unsigned int)(unsigned short)s) << 16;
    return x.f;
}

// ---------------- init: zero Z, label_sum, cnt, cursor ----------------
__global__ void init_kernel(float* Z, float* lsum, int* cnt, int* cur, int N) {
    int t = blockIdx.x * 256 + threadIdx.x;
    if (t < N) Z[t] = 0.0f;
    if (t < NCLS) { lsum[t] = 0.0f; cnt[t] = 0; cur[t] = 0; }
}

// ---------------- cvt: fp32 -> bf16 (RTN), 8 elems/thread ----------------
__global__ __launch_bounds__(256) void cvt_kernel(const float* __restrict__ emb,
                                                  short* __restrict__ embb, int total) {
    int base = (blockIdx.x * 256 + threadIdx.x) * 8;
    if (base >= total) return;
    float4 v0 = *(const float4*)&emb[base];
    float4 v1 = *(const float4*)&emb[base + 4];
    short8 o;
    __hip_bfloat16 h;
    h = __float2bfloat16(v0.x); o[0] = *(short*)&h;
    h = __float2bfloat16(v0.y); o[1] = *(short*)&h;
    h = __float2bfloat16(v0.z); o[2] = *(short*)&h;
    h = __float2bfloat16(v0.w); o[3] = *(short*)&h;
    h = __float2bfloat16(v1.x); o[4] = *(short*)&h;
    h = __float2bfloat16(v1.y); o[5] = *(short*)&h;
    h = __float2bfloat16(v1.z); o[6] = *(short*)&h;
    h = __float2bfloat16(v1.w); o[7] = *(short*)&h;
    *(short8*)&embb[base] = o;
}

// ---------------- prep: sq[i] = ||e_i||^2 (fp32, exact), count labels ----------------
__global__ __launch_bounds__(256) void prep_kernel(const float* __restrict__ emb,
                                                   const int* __restrict__ lab,
                                                   float* __restrict__ sq,
                                                   int* __restrict__ cnt, int N) {
    int w = (blockIdx.x * blockDim.x + threadIdx.x) >> 6;
    int lane = threadIdx.x & 63;
    if (w >= N) return;
    float x0 = emb[w * KD + lane];
    float x1 = emb[w * KD + 64 + lane];
    float s = x0 * x0 + x1 * x1;
    for (int m = 32; m; m >>= 1) s += __shfl_xor(s, m, 64);
    if (lane == 0) {
        sq[w] = s;
        atomicAdd(&cnt[lab[w]], 1);
    }
}

// ---------------- offsets: serial exclusive scan over 64 counts ----------------
__global__ void off_kernel(const int* __restrict__ cnt, int* __restrict__ off) {
    if (threadIdx.x == 0) {
        int s = 0;
        for (int c = 0; c < NCLS; ++c) { off[c] = s; s += cnt[c]; }
    }
}

// ---------------- scatter: member lists per label ----------------
__global__ void scatter_kernel(const int* __restrict__ lab, const int* __restrict__ off,
                               int* __restrict__ cur, int* __restrict__ list, int N) {
    int i = blockIdx.x * 256 + threadIdx.x;
    if (i < N) {
        int c = lab[i];
        int p = atomicAdd(&cur[c], 1);
        list[off[c] + p] = i;
    }
}

// ---------------- MFMA Z pass ----------------
// Z[i] = sum_{j: lab[j]!=lab[i]} exp(sq[i]+sq[j]-2*dot(e_i,e_j))
// 128x128 output tile per block, 4 waves as 2x2 of 64x64, mfma_f32_16x16x32_bf16.
// A tile staged once; B tile per j-iter via global_load_lds(16B) with
// pre-swizzled global source: LDS[row][c] = G[row][c^(row&7)] (chunk = 16B of 8 bf16).
__global__ __launch_bounds__(256, 2) void zmfma_kernel(const short* __restrict__ embb,
                                                       const int* __restrict__ lab,
                                                       const float* __restrict__ sq,
                                                       float* __restrict__ Z, int N) {
    __shared__ short8 As8[128 * 16];  // 32 KB
    __shared__ short8 Bs8[128 * 16];  // 32 KB

    const int tid = threadIdx.x;
    const int w = tid >> 6, l = tid & 63;
    const int wr = w >> 1, wc = w & 1;
    const int i0 = blockIdx.y * 128;
    const int jBeg = blockIdx.x * (N / JSPLIT);
    const short8* embv = (const short8*)embb;

    // stage A tile (rows i0..i0+127), swizzled source
#pragma unroll
    for (int it = 0; it < 8; ++it) {
        int lr = w * 32 + it * 4 + (l >> 4);
        int c = (l & 15) ^ (lr & 7);
        gload_lds16(embv + (size_t)(i0 + lr) * 16 + c, &As8[w * 512 + it * 64]);
    }

    // per-lane i metadata: i = i0 + wr*64 + mi*16 + (l>>4)*4 + r
    float sqi[4][4]; int labi[4][4];
#pragma unroll
    for (int mi = 0; mi < 4; ++mi)
#pragma unroll
        for (int r = 0; r < 4; ++r) {
            int i = i0 + wr * 64 + mi * 16 + (l >> 4) * 4 + r;
            sqi[mi][r] = sq[i];
            labi[mi][r] = lab[i];
        }
    float zsum[4][4];
#pragma unroll
    for (int mi = 0; mi < 4; ++mi)
#pragma unroll
        for (int r = 0; r < 4; ++r) zsum[mi][r] = 0.f;

    __syncthreads();  // A ready

    const int nj = N / JSPLIT / 128;
    for (int jt = 0; jt < nj; ++jt) {
        int j0 = jBeg + jt * 128;
        // stage B tile
#pragma unroll
        for (int it = 0; it < 8; ++it) {
            int lr = w * 32 + it * 4 + (l >> 4);
            int c = (l & 15) ^ (lr & 7);
            gload_lds16(embv + (size_t)(j0 + lr) * 16 + c, &Bs8[w * 512 + it * 64]);
        }
        __syncthreads();  // B ready (drains vmcnt)

        f32x4 acc[4][4];
#pragma unroll
        for (int mi = 0; mi < 4; ++mi)
#pragma unroll
            for (int ni = 0; ni < 4; ++ni) acc[mi][ni] = (f32x4){0.f, 0.f, 0.f, 0.f};

#pragma unroll
        for (int ks = 0; ks < 4; ++ks) {
            short8 af[4], bf[4];
            int kc = ks * 4 + (l >> 4);
#pragma unroll
            for (int mi = 0; mi < 4; ++mi) {
                int row = wr * 64 + mi * 16 + (l & 15);
                af[mi] = As8[row * 16 + (kc ^ (row & 7))];
            }
#pragma unroll
            for (int ni = 0; ni < 4; ++ni) {
                int row = wc * 64 + ni * 16 + (l & 15);
                bf[ni] = Bs8[row * 16 + (kc ^ (row & 7))];
            }
#pragma unroll
            for (int mi = 0; mi < 4; ++mi)
#pragma unroll
                for (int ni = 0; ni < 4; ++ni)
                    acc[mi][ni] = __builtin_amdgcn_mfma_f32_16x16x32_bf16(af[mi], bf[ni], acc[mi][ni], 0, 0, 0);
        }

        // epilogue: D = sqi + sqj - 2*dot; masked exp; accumulate per-i
        float sqj[4]; int labj[4];
#pragma unroll
        for (int ni = 0; ni < 4; ++ni) {
            int j = j0 + wc * 64 + ni * 16 + (l & 15);
            sqj[ni] = sq[j];
            labj[ni] = lab[j];
        }
#pragma unroll
        for (int mi = 0; mi < 4; ++mi)
#pragma unroll
            for (int ni = 0; ni < 4; ++ni)
#pragma unroll
                for (int r = 0; r < 4; ++r) {
                    float D = fmaf(-2.f, acc[mi][ni][r], sqi[mi][r] + sqj[ni]);
                    float e = __expf(D);
                    zsum[mi][r] += (labj[ni] != labi[mi][r]) ? e : 0.f;
                }
        __syncthreads();  // everyone done reading Bs before next stage
    }

    // reduce across the 16 lanes sharing each i (bits 0..3 of lane), atomic into Z
#pragma unroll
    for (int mi = 0; mi < 4; ++mi)
#pragma unroll
        for (int r = 0; r < 4; ++r) {
            float v = zsum[mi][r];
            v += __shfl_xor(v, 1, 64);
            v += __shfl_xor(v, 2, 64);
            v += __shfl_xor(v, 4, 64);
            v += __shfl_xor(v, 8, 64);
            if ((l & 15) == 0)
                atomicAdd(&Z[i0 + wr * 64 + mi * 16 + (l >> 4) * 4 + r], v);
        }
}

// ---------------- pairs v2: LDS-staged per-label member rows (bf16) ----------------
// grid = 64 labels * 4 stripes; block stages label's rows once, pairs read LDS.
__global__ __launch_bounds__(256) void pair2_kernel(const short* __restrict__ embb,
                                                    const float* __restrict__ sq,
                                                    const float* __restrict__ Z,
                                                    const int* __restrict__ cnt,
                                                    const int* __restrict__ off,
                                                    const int* __restrict__ list,
                                                    float* __restrict__ lsum) {
    __shared__ short Ms[PCAP * 132];  // row stride 132 shorts (264B): 8B-aligned, bank-friendly
    __shared__ float red[4];
    int c = blockIdx.x & (NCLS - 1);
    int s = blockIdx.x >> 6;
    int k = cnt[c];
    int base = off[c];
    int kc = min(k, PCAP);

    // stage kc rows (16B global chunks -> two 8B LDS stores)
    for (int idx = threadIdx.x; idx < kc * 16; idx += 256) {
        int r = idx >> 4, ch = idx & 15;
        const short4_t* gp = (const short4_t*)(embb + (size_t)list[base + r] * KD + ch * 8);
        *(short4_t*)&Ms[r * 132 + ch * 8] = gp[0];
        *(short4_t*)&Ms[r * 132 + ch * 8 + 4] = gp[1];
    }
    __syncthreads();

    long total = (long)k * k;
    float part = 0.f;
    for (long t = threadIdx.x + (long)s * 256; t < total; t += 1024) {
        int p = (int)(t / k);
        int q = (int)(t - (long)p * k);
        if (p >= q) continue;
        int a = list[base + p];
        int b = list[base + q];
        float dot = 0.f;
        if (p < PCAP && q < PCAP) {
            const short4_t* pa = (const short4_t*)&Ms[p * 132];
            const short4_t* pb = (const short4_t*)&Ms[q * 132];
#pragma unroll 8
            for (int u = 0; u < KD / 4; ++u) {
                short4_t va = pa[u], vb = pb[u];
                dot += b2f(va[0]) * b2f(vb[0]) + b2f(va[1]) * b2f(vb[1]) +
                       b2f(va[2]) * b2f(vb[2]) + b2f(va[3]) * b2f(vb[3]);
            }
        } else {  // statistically never (needs label count > 224); correctness fallback
            const short4_t* pa = (const short4_t*)(embb + (size_t)a * KD);
            const short4_t* pb = (const short4_t*)(embb + (size_t)b * KD);
            for (int u = 0; u < KD / 4; ++u) {
                short4_t va = pa[u], vb = pb[u];
                dot += b2f(va[0]) * b2f(vb[0]) + b2f(va[1]) * b2f(vb[1]) +
                       b2f(va[2]) * b2f(vb[2]) + b2f(va[3]) * b2f(vb[3]);
            }
        }
        float D = sq[a] + sq[b] - 2.0f * dot;
        int anc = min(a, b);
        part += log1pf(Z[anc] * __expf(-D));
    }

    for (int m = 32; m; m >>= 1) part += __shfl_xor(part, m, 64);
    int lane = threadIdx.x & 63;
    int wv = threadIdx.x >> 6;
    if (lane == 0) red[wv] = part;
    __syncthreads();
    if (threadIdx.x == 0)
        atomicAdd(&lsum[c], red[0] + red[1] + red[2] + red[3]);
}

// ---------------- finalize: per-label mean, mean over valid labels ----------------
__global__ void fin_kernel(const float* __restrict__ lsum, const int* __restrict__ cnt,
                           float* __restrict__ out) {
    int c = threadIdx.x;
    float mean = 0.f;
    int valid = 0;
    if (c < NCLS) {
        long k = cnt[c];
        long np = k * (k - 1) / 2;
        if (np > 0) { mean = lsum[c] / (float)np; valid = 1; }
    }
    float sm = mean;
    int sv = valid;
    for (int m = 32; m; m >>= 1) {
        sm += __shfl_xor(sm, m, 64);
        sv += __shfl_xor(sv, m, 64);
    }
    if (c == 0) out[0] = sm / (float)max(sv, 1);
}

extern "C" void kernel_launch(void* const* d_in, const int* in_sizes, int n_in,
                              void* d_out, int out_size, void* d_ws, size_t ws_size,
                              hipStream_t stream) {
    const float* emb = (const float*)d_in[0];
    const int* lab = (const int*)d_in[1];
    float* out = (float*)d_out;
    const int N = in_sizes[1];  // 8192
    const int total = N * KD;

    // workspace layout (4B units)
    float* ws = (float*)d_ws;
    float* sq = ws;                         // N floats
    float* Z = ws + N;                      // N floats
    float* lsum = ws + 2 * N;               // 64
    int* cnt = (int*)(ws + 2 * N + NCLS);   // 64
    int* off = cnt + NCLS;                  // 64
    int* cur = off + NCLS;                  // 64
    int* list = cur + NCLS;                 // N
    short* embb = (short*)(list + N);       // N*KD bf16 (2 MB), 16B-aligned

    init_kernel<<<(N + 255) / 256, 256, 0, stream>>>(Z, lsum, cnt, cur, N);
    cvt_kernel<<<(total / 8 + 255) / 256, 256, 0, stream>>>(emb, embb, total);
    prep_kernel<<<N / 4, 256, 0, stream>>>(emb, lab, sq, cnt, N);
    off_kernel<<<1, 64, 0, stream>>>(cnt, off);
    scatter_kernel<<<(N + 255) / 256, 256, 0, stream>>>(lab, off, cur, list, N);
    dim3 zgrid(JSPLIT, N / 128);
    zmfma_kernel<<<zgrid, 256, 0, stream>>>(embb, lab, sq, Z, N);
    pair2_kernel<<<NCLS * 4, 256, 0, stream>>>(embb, sq, Z, cnt, off, list, lsum);
    fin_kernel<<<1, 64, 0, stream>>>(lsum, cnt, out);
}

// Round 3
// 160.796 us; speedup vs baseline: 3.0731x; 1.1733x over previous
//
#include <hip/hip_runtime.h>
#include <hip/hip_bf16.h>
#include <math.h>

// Problem constants (FunctionNPairLoss): N=8192 rows, K=128 dims, 64 classes.
#define KD 128
#define NCLS 64
#define JSPLIT 8

typedef __attribute__((ext_vector_type(8))) short short8;
typedef __attribute__((ext_vector_type(4))) float f32x4;

__device__ inline void gload_lds16(const void* g, void* l) {
    __builtin_amdgcn_global_load_lds((const __attribute__((address_space(1))) unsigned int*)g,
                                     (__attribute__((address_space(3))) unsigned int*)l,
                                     16, 0, 0);
}

// ---------------- fused cvt+prep: bf16 convert, sq = ||row||^2, label counts ----------------
// one wave per row; lane handles 2 consecutive elems (8B load, 4B packed store)
__global__ __launch_bounds__(256) void cvtprep_kernel(const float* __restrict__ emb,
                                                      const int* __restrict__ lab,
                                                      short* __restrict__ embb,
                                                      float* __restrict__ sq,
                                                      int* __restrict__ cnt, int N) {
    int w = (blockIdx.x * 256 + threadIdx.x) >> 6;
    int l = threadIdx.x & 63;
    if (w >= N) return;
    float2 v = *(const float2*)&emb[(size_t)w * KD + l * 2];
    float s = v.x * v.x + v.y * v.y;
    __hip_bfloat16 h0 = __float2bfloat16(v.x);
    __hip_bfloat16 h1 = __float2bfloat16(v.y);
    unsigned int pk = ((unsigned int)*(unsigned short*)&h1 << 16) | (unsigned int)*(unsigned short*)&h0;
    *(unsigned int*)&embb[(size_t)w * KD + l * 2] = pk;
    for (int m = 32; m; m >>= 1) s += __shfl_xor(s, m, 64);
    if (l == 0) {
        sq[w] = s;
        atomicAdd(&cnt[lab[w]], 1);
    }
}

// ---------------- scan: 64-lane exclusive prefix over label counts ----------------
__global__ void scan_kernel(const int* __restrict__ cnt, int* __restrict__ off) {
    int l = threadIdx.x;
    int v = cnt[l];
    int s = v;
    for (int m = 1; m < 64; m <<= 1) {
        int t = __shfl_up(s, m, 64);
        if (l >= m) s += t;
    }
    off[l] = s - v;
}

// ---------------- scatter: member lists per label ----------------
__global__ void scatter_kernel(const int* __restrict__ lab, const int* __restrict__ off,
                               int* __restrict__ cur, int* __restrict__ list, int N) {
    int i = blockIdx.x * 256 + threadIdx.x;
    if (i < N) {
        int c = lab[i];
        int p = atomicAdd(&cur[c], 1);
        list[off[c] + p] = i;
    }
}

// ---------------- MFMA Z pass ----------------
// Z[i] = sum_{j: lab[j]!=lab[i]} exp(sq[i]+sq[j]-2*dot(e_i,e_j))
// 128x128 tile per block, 4 waves 2x2, mfma_f32_16x16x32_bf16, A-frags hoisted to regs.
__global__ __launch_bounds__(256, 2) void zmfma_kernel(const short* __restrict__ embb,
                                                       const int* __restrict__ lab,
                                                       const float* __restrict__ sq,
                                                       float* __restrict__ Z, int N) {
    __shared__ short8 As8[128 * 16];  // 32 KB
    __shared__ short8 Bs8[128 * 16];  // 32 KB

    const int tid = threadIdx.x;
    const int w = tid >> 6, l = tid & 63;
    const int wr = w >> 1, wc = w & 1;
    const int i0 = blockIdx.y * 128;
    const int jBeg = blockIdx.x * (N / JSPLIT);
    const short8* embv = (const short8*)embb;

    // stage A tile (rows i0..i0+127), swizzled source: LDS[row][c] = G[row][c^(row&7)]
#pragma unroll
    for (int it = 0; it < 8; ++it) {
        int lr = w * 32 + it * 4 + (l >> 4);
        int c = (l & 15) ^ (lr & 7);
        gload_lds16(embv + (size_t)(i0 + lr) * 16 + c, &As8[w * 512 + it * 64]);
    }

    float sqi[4][4]; int labi[4][4];
#pragma unroll
    for (int mi = 0; mi < 4; ++mi)
#pragma unroll
        for (int r = 0; r < 4; ++r) {
            int i = i0 + wr * 64 + mi * 16 + (l >> 4) * 4 + r;
            sqi[mi][r] = sq[i];
            labi[mi][r] = lab[i];
        }
    float zsum[4][4];
#pragma unroll
    for (int mi = 0; mi < 4; ++mi)
#pragma unroll
        for (int r = 0; r < 4; ++r) zsum[mi][r] = 0.f;

    __syncthreads();  // A staged

    // hoist A fragments (loop-invariant over j)
    short8 af[4][4];
#pragma unroll
    for (int mi = 0; mi < 4; ++mi) {
        int row = wr * 64 + mi * 16 + (l & 15);
        int rs = row * 16, rx = row & 7;
#pragma unroll
        for (int ks = 0; ks < 4; ++ks) {
            int kc = ks * 4 + (l >> 4);
            af[mi][ks] = As8[rs + (kc ^ rx)];
        }
    }

    const int nj = N / JSPLIT / 128;
    for (int jt = 0; jt < nj; ++jt) {
        int j0 = jBeg + jt * 128;
#pragma unroll
        for (int it = 0; it < 8; ++it) {
            int lr = w * 32 + it * 4 + (l >> 4);
            int c = (l & 15) ^ (lr & 7);
            gload_lds16(embv + (size_t)(j0 + lr) * 16 + c, &Bs8[w * 512 + it * 64]);
        }
        __syncthreads();  // B ready

        f32x4 acc[4][4];
#pragma unroll
        for (int mi = 0; mi < 4; ++mi)
#pragma unroll
            for (int ni = 0; ni < 4; ++ni) acc[mi][ni] = (f32x4){0.f, 0.f, 0.f, 0.f};

#pragma unroll
        for (int ks = 0; ks < 4; ++ks) {
            short8 bf[4];
            int kc = ks * 4 + (l >> 4);
#pragma unroll
            for (int ni = 0; ni < 4; ++ni) {
                int row = wc * 64 + ni * 16 + (l & 15);
                bf[ni] = Bs8[row * 16 + (kc ^ (row & 7))];
            }
#pragma unroll
            for (int mi = 0; mi < 4; ++mi)
#pragma unroll
                for (int ni = 0; ni < 4; ++ni)
                    acc[mi][ni] = __builtin_amdgcn_mfma_f32_16x16x32_bf16(af[mi][ks], bf[ni], acc[mi][ni], 0, 0, 0);
        }

        // epilogue: D = sqi + sqj - 2*dot; masked exp; accumulate per-i
        float sqj[4]; int labj[4];
#pragma unroll
        for (int ni = 0; ni < 4; ++ni) {
            int j = j0 + wc * 64 + ni * 16 + (l & 15);
            sqj[ni] = sq[j];
            labj[ni] = lab[j];
        }
#pragma unroll
        for (int mi = 0; mi < 4; ++mi)
#pragma unroll
            for (int ni = 0; ni < 4; ++ni)
#pragma unroll
                for (int r = 0; r < 4; ++r) {
                    float D = fmaf(-2.f, acc[mi][ni][r], sqi[mi][r] + sqj[ni]);
                    float e = __expf(D);
                    zsum[mi][r] += (labj[ni] != labi[mi][r]) ? e : 0.f;
                }
        __syncthreads();  // done reading Bs
    }

    // reduce across the 16 lanes sharing each i, atomic into Z
#pragma unroll
    for (int mi = 0; mi < 4; ++mi)
#pragma unroll
        for (int r = 0; r < 4; ++r) {
            float v = zsum[mi][r];
            v += __shfl_xor(v, 1, 64);
            v += __shfl_xor(v, 2, 64);
            v += __shfl_xor(v, 4, 64);
            v += __shfl_xor(v, 8, 64);
            if ((l & 15) == 0)
                atomicAdd(&Z[i0 + wr * 64 + mi * 16 + (l >> 4) * 4 + r], v);
        }
}

// ---------------- pair pass v3: block-diagonal MFMA over per-label member lists ----------------
// grid (3, NCLS): quadrants (qi,qj) of a 256-row cap: 0=(0,0), 1=(0,1), 2=(1,1).
// Block stages its quadrant's rows (gathered via list, padded with last row),
// MFMA 128x128 pairwise dots, epilogue: p<q mask, log(1 + Z[anchor]*exp(-D)).
__global__ __launch_bounds__(256, 2) void pair3_kernel(const short* __restrict__ embb,
                                                       const float* __restrict__ sq,
                                                       const float* __restrict__ Z,
                                                       const int* __restrict__ cnt,
                                                       const int* __restrict__ off,
                                                       const int* __restrict__ list,
                                                       float* __restrict__ lsum) {
    __shared__ short8 As8[128 * 16];
    __shared__ short8 Bs8[128 * 16];
    __shared__ int glA[128], glB[128];
    __shared__ float sqA[128], sqB[128], zA[128], zB[128];
    __shared__ float red[4];

    const int qq = blockIdx.x, c = blockIdx.y;
    const int qi = (qq == 2) ? 1 : 0;
    const int qj = (qq == 0) ? 0 : 1;
    const int k = cnt[c], base = off[c];
    if (k <= 1 || qi * 128 >= k || qj * 128 >= k) return;  // uniform across block

    const int tid = threadIdx.x;
    const int w = tid >> 6, l = tid & 63;
    const int wr = w >> 1, wc = w & 1;
    const short8* embv = (const short8*)embb;

    // stage per-row metadata
    if (tid < 128) {
        int p = min(qi * 128 + tid, k - 1);
        int a = list[base + p];
        glA[tid] = a; sqA[tid] = sq[a]; zA[tid] = Z[a];
    } else {
        int t2 = tid - 128;
        int q = min(qj * 128 + t2, k - 1);
        int b = list[base + q];
        glB[t2] = b; sqB[t2] = sq[b]; zB[t2] = Z[b];
    }

    // stage A and B row tiles (gathered), swizzled like zmfma
#pragma unroll
    for (int it = 0; it < 8; ++it) {
        int lr = w * 32 + it * 4 + (l >> 4);
        int ch = (l & 15) ^ (lr & 7);
        int srcA = list[base + min(qi * 128 + lr, k - 1)];
        gload_lds16(embv + (size_t)srcA * 16 + ch, &As8[w * 512 + it * 64]);
    }
#pragma unroll
    for (int it = 0; it < 8; ++it) {
        int lr = w * 32 + it * 4 + (l >> 4);
        int ch = (l & 15) ^ (lr & 7);
        int srcB = list[base + min(qj * 128 + lr, k - 1)];
        gload_lds16(embv + (size_t)srcB * 16 + ch, &Bs8[w * 512 + it * 64]);
    }
    __syncthreads();

    f32x4 acc[4][4];
#pragma unroll
    for (int mi = 0; mi < 4; ++mi)
#pragma unroll
        for (int ni = 0; ni < 4; ++ni) acc[mi][ni] = (f32x4){0.f, 0.f, 0.f, 0.f};

#pragma unroll
    for (int ks = 0; ks < 4; ++ks) {
        short8 af[4], bf[4];
        int kc = ks * 4 + (l >> 4);
#pragma unroll
        for (int mi = 0; mi < 4; ++mi) {
            int row = wr * 64 + mi * 16 + (l & 15);
            af[mi] = As8[row * 16 + (kc ^ (row & 7))];
        }
#pragma unroll
        for (int ni = 0; ni < 4; ++ni) {
            int row = wc * 64 + ni * 16 + (l & 15);
            bf[ni] = Bs8[row * 16 + (kc ^ (row & 7))];
        }
#pragma unroll
        for (int mi = 0; mi < 4; ++mi)
#pragma unroll
            for (int ni = 0; ni < 4; ++ni)
                acc[mi][ni] = __builtin_amdgcn_mfma_f32_16x16x32_bf16(af[mi], bf[ni], acc[mi][ni], 0, 0, 0);
    }

    // epilogue: per-pair loss
    float part = 0.f;
#pragma unroll
    for (int mi = 0; mi < 4; ++mi)
#pragma unroll
        for (int ni = 0; ni < 4; ++ni) {
            int qL = wc * 64 + ni * 16 + (l & 15);
            int q = qj * 128 + qL;
#pragma unroll
            for (int r = 0; r < 4; ++r) {
                int pL = wr * 64 + mi * 16 + (l >> 4) * 4 + r;
                int p = qi * 128 + pL;
                bool valid = (p < q) && (q < k);
                float D = fmaf(-2.f, acc[mi][ni][r], sqA[pL] + sqB[qL]);
                int a = glA[pL], b = glB[qL];
                float z = (a < b) ? zA[pL] : zB[qL];
                float x = valid ? z * __expf(-D) : 0.f;
                part += __logf(1.f + x);
            }
        }

    for (int m = 32; m; m >>= 1) part += __shfl_xor(part, m, 64);
    if (l == 0) red[w] = part;
    __syncthreads();
    if (tid == 0)
        atomicAdd(&lsum[c], red[0] + red[1] + red[2] + red[3]);
}

// ---------------- finalize: per-label mean, mean over valid labels ----------------
__global__ void fin_kernel(const float* __restrict__ lsum, const int* __restrict__ cnt,
                           float* __restrict__ out) {
    int c = threadIdx.x;
    float mean = 0.f;
    int valid = 0;
    if (c < NCLS) {
        long k = cnt[c];
        long np = k * (k - 1) / 2;
        if (np > 0) { mean = lsum[c] / (float)np; valid = 1; }
    }
    float sm = mean;
    int sv = valid;
    for (int m = 32; m; m >>= 1) {
        sm += __shfl_xor(sm, m, 64);
        sv += __shfl_xor(sv, m, 64);
    }
    if (c == 0) out[0] = sm / (float)max(sv, 1);
}

extern "C" void kernel_launch(void* const* d_in, const int* in_sizes, int n_in,
                              void* d_out, int out_size, void* d_ws, size_t ws_size,
                              hipStream_t stream) {
    const float* emb = (const float*)d_in[0];
    const int* lab = (const int*)d_in[1];
    float* out = (float*)d_out;
    const int N = in_sizes[1];  // 8192

    // workspace layout (4B units); [Z | lsum | cnt | cur] contiguous for one memset
    float* ws = (float*)d_ws;
    float* Z = ws;                        // N
    float* lsum = ws + N;                 // 64
    int* cnt = (int*)(ws + N + NCLS);     // 64
    int* cur = cnt + NCLS;                // 64
    int* off = cur + NCLS;                // 64
    int* list = off + NCLS;               // N
    float* sq = (float*)(list + N);       // N
    short* embb = (short*)(sq + N);       // N*KD bf16 (2 MB), 16B-aligned

    hipMemsetAsync(Z, 0, (size_t)(N + 3 * NCLS) * 4, stream);
    cvtprep_kernel<<<N / 4, 256, 0, stream>>>(emb, lab, embb, sq, cnt, N);
    scan_kernel<<<1, 64, 0, stream>>>(cnt, off);
    scatter_kernel<<<(N + 255) / 256, 256, 0, stream>>>(lab, off, cur, list, N);
    dim3 zgrid(JSPLIT, N / 128);
    zmfma_kernel<<<zgrid, 256, 0, stream>>>(embb, lab, sq, Z, N);
    dim3 pgrid(3, NCLS);
    pair3_kernel<<<pgrid, 256, 0, stream>>>(embb, sq, Z, cnt, off, list, lsum);
    fin_kernel<<<1, 64, 0, stream>>>(lsum, cnt, out);
}